// Round 1
// 850.588 us; speedup vs baseline: 1.0297x; 1.0297x over previous
//
#include <hip/hip_runtime.h>
#include <math.h>

#define D 64
#define MIN_NORM 1e-15f

#define RCP(x)  __builtin_amdgcn_rcpf(x)
#define RSQ(x)  __builtin_amdgcn_rsqf(x)

// ---------------- DPP butterfly within 16-lane rows ----------------
template <int CTRL>
__device__ __forceinline__ float dpp_sum_step(float v) {
    int iv = __builtin_bit_cast(int, v);
    int sh = __builtin_amdgcn_update_dpp(0, iv, CTRL, 0xf, 0xf, true);
    return v + __builtin_bit_cast(float, sh);
}
#define DPP_XOR1  0xB1   // quad_perm [1,0,3,2]
#define DPP_XOR2  0x4E   // quad_perm [2,3,0,1]
#define DPP_HMIR  0x141  // row_half_mirror
#define DPP_MIR   0x140  // row_mirror

__device__ __forceinline__ float row16_sum(float v) {
    v = dpp_sum_step<DPP_XOR1>(v);
    v = dpp_sum_step<DPP_XOR2>(v);
    v = dpp_sum_step<DPP_HMIR>(v);
    v = dpp_sum_step<DPP_MIR>(v);
    return v;
}

// ---------------- fast transcendentals (args >= 0) ----------------

__device__ __forceinline__ float fast_tanh_pos(float x) {
    float t = __expf(-2.0f * x);
    return (1.0f - t) * RCP(1.0f + t);
}

__device__ __forceinline__ float fast_atanh(float x) {
    return 0.5f * __logf((1.0f + x) * RCP(1.0f - x));
}

// ---------------- RGAT edge kernel: 16 lanes/edge, STRIDED dim layout ------
// dim = c*16 + sub. Loads and atomic stores are one full contiguous 64B
// cacheline per instruction per edge. No transpose, no write inflation.

__global__ __launch_bounds__(256) void rgat_edge_kernel(
    const float* __restrict__ ent, const float* __restrict__ rel,
    const int* __restrict__ head, const int* __restrict__ tail,
    const int* __restrict__ etype,
    float* __restrict__ sums, float* __restrict__ cnt, int n_edges)
{
    int e = blockIdx.x * 16 + (threadIdx.x >> 4);
    int ec = min(e, n_edges - 1);          // clamp; no early return (DPP below)
    bool active = (e < n_edges);
    int sub = threadIdx.x & 15;

    int h = head[ec];
    int t = tail[ec];
    int r = etype[ec] - 1;

    const float* hp = ent + (size_t)h * D + sub;
    const float* tp = ent + (size_t)t * D + sub;
    const float* rp = rel + (size_t)r * D + sub;
    float hex = hp[0], hey = hp[16], hez = hp[32], hew = hp[48];
    float tex = tp[0], tey = tp[16], tez = tp[32], tew = tp[48];
    float rex = rp[0], rey = rp[16], rez = rp[32], rew = rp[48];

    float v0 = hex*hex + hey*hey + hez*hez + hew*hew;
    float v1 = tex*tex + tey*tey + tez*tez + tew*tew;
    float v2 = rex*rex + rey*rey + rez*rez + rew*rew;
    float v3 = hex*tex + hey*tey + hez*tez + hew*tew;
    float v4 = hex*rex + hey*rey + hez*rez + hew*rew;
    float v5 = tex*rex + tey*rey + tez*rez + tew*rew;
    float HE2 = row16_sum(v0);
    float TE2 = row16_sum(v1);
    float RE2 = row16_sum(v2);
    float HT  = row16_sum(v3);
    float HR  = row16_sum(v4);
    float TR  = row16_sum(v5);

    // ---- scalar chain (uniform within each 16-lane group) ----
    float S2 = TE2 + 2.0f * TR + RE2;
    float ricci_k = 1e-7f * RSQ(fmaxf(S2, 1e-24f));

    float HE2g = fmaxf(HE2, 1e-30f);
    float rNhe = RSQ(HE2g);
    float Nhe  = HE2g * rNhe;
    float a = fast_tanh_pos(Nhe) * rNhe;
    float HH2 = a * a * HE2;
    float mterm = fmaxf(1.0f - HH2, MIN_NORM);   // = 2/lam
    float rmterm = RCP(mterm);

    float TE2g = fmaxf(TE2, 1e-30f);
    float rNte = RSQ(TE2g);
    float b = fast_tanh_pos(TE2g * rNte * rmterm) * rNte;
    float RE2g = fmaxf(RE2, 1e-30f);
    float rNre = RSQ(RE2g);
    float c = fast_tanh_pos(RE2g * rNre * rmterm) * rNre;

    float y2t = b * b * TE2, xyt = a * b * HT;
    float A1 = 1.0f + 2.0f * xyt + y2t, B1 = 1.0f - HH2;
    float r_d1 = RCP(fmaxf(1.0f + 2.0f * xyt + HH2 * y2t, MIN_NORM));
    float p1 = A1 * a * r_d1, q1 = B1 * b * r_d1;
    float HT2 = fmaxf((A1*A1*HH2 + 2.0f*A1*B1*xyt + B1*B1*y2t) * r_d1 * r_d1, 0.0f);

    float y2r = c * c * RE2, xyr = a * c * HR;
    float A2 = 1.0f + 2.0f * xyr + y2r, B2 = 1.0f - HH2;
    float r_d2 = RCP(fmaxf(1.0f + 2.0f * xyr + HH2 * y2r, MIN_NORM));
    float p2 = A2 * a * r_d2, q2 = B2 * c * r_d2;
    float HR2 = fmaxf((A2*A2*HH2 + 2.0f*A2*B2*xyr + B2*B2*y2r) * r_d2 * r_d2, 0.0f);

    float xy3 = p1*p2*HE2 + p1*q2*HR + q1*p2*HT + q1*q2*TR;
    float A3 = 1.0f + 2.0f * xy3 + HR2, B3 = 1.0f - HT2;
    float r_d3 = RCP(fmaxf(1.0f + 2.0f * xy3 + HT2 * HR2, MIN_NORM));
    float al = (A3 * p1 + B3 * p2) * r_d3;
    float be = A3 * q1 * r_d3;
    float ga = B3 * q2 * r_d3;
    float R2 = fmaxf((A3*A3*HT2 + 2.0f*A3*B3*xy3 + B3*B3*HR2) * r_d3 * r_d3, 0.0f);

    float R2g = fmaxf(R2, 1e-30f);
    float rNr = RSQ(R2g);
    float Nr  = R2g * rNr;
    const float maxn = 1.0f - 1e-3f;
    if (Nr > maxn) {
        float s = maxn * rNr;
        al *= s; be *= s; ga *= s;
        R2 = maxn * maxn;
    }

    float dhr = a * (al * HE2 + be * HT + ga * HR);
    float xy4 = -dhr;
    float A4 = 1.0f + 2.0f * xy4 + R2, B4 = 1.0f - HH2;
    float r_d4 = RCP(fmaxf(1.0f + 2.0f * xy4 + HH2 * R2, MIN_NORM));
    float sh = (-A4 * a + B4 * al) * r_d4;
    float st = B4 * be * r_d4;
    float sr = B4 * ga * r_d4;
    float SUB2 = fmaxf((A4*A4*HH2 + 2.0f*A4*B4*xy4 + B4*B4*R2) * r_d4 * r_d4, 0.0f);

    float SUB2g = fmaxf(SUB2, 1e-30f);
    float rNsub = RSQ(SUB2g);
    float Nsub  = SUB2g * rNsub;
    float k = mterm * fast_atanh(fminf(Nsub, 1.0f - 1e-5f)) * rNsub;

    float kh = k * sh;
    float kt = k * st + ricci_k;
    float kr = k * sr + ricci_k;

    float ox = fmaxf(kh*hex + kt*tex + kr*rex, 0.0f);
    float oy = fmaxf(kh*hey + kt*tey + kr*rey, 0.0f);
    float oz = fmaxf(kh*hez + kt*tez + kr*rez, 0.0f);
    float ow = fmaxf(kh*hew + kt*tew + kr*rew, 0.0f);

    if (active) {
        float* dst = sums + (size_t)h * D + sub;
        atomicAdd(dst +  0, ox);
        atomicAdd(dst + 16, oy);
        atomicAdd(dst + 32, oz);
        atomicAdd(dst + 48, ow);
        if (sub == 0) atomicAdd(&cnt[h], 1.0f);
    }
}

// ---------------- per-entity finalize: mean -> l2norm -> residual ----------------

__global__ __launch_bounds__(256) void finalize_hop_kernel(
    const float* __restrict__ sums, const float* __restrict__ cnt,
    const float* __restrict__ prev_res,
    float* __restrict__ ent_out, float* __restrict__ res_out, int n_ent)
{
    int row = blockIdx.x * 16 + (threadIdx.x >> 4);
    if (row >= n_ent) return;
    int sub = threadIdx.x & 15;

    float rc = RCP(fmaxf(cnt[row], 1.0f));
    float4 m = ((const float4*)(sums + (size_t)row * D))[sub];
    m.x *= rc; m.y *= rc; m.z *= rc; m.w *= rc;

    float M2 = row16_sum(m.x*m.x + m.y*m.y + m.z*m.z + m.w*m.w);
    float rn = RSQ(fmaxf(M2, 1e-24f));
    float4 v = make_float4(m.x*rn, m.y*rn, m.z*rn, m.w*rn);

    ((float4*)(ent_out + (size_t)row * D))[sub] = v;
    float4 p = ((const float4*)(prev_res + (size_t)row * D))[sub];
    ((float4*)(res_out + (size_t)row * D))[sub] =
        make_float4(0.5f*p.x + v.x, 0.5f*p.y + v.y, 0.5f*p.z + v.z, 0.5f*p.w + v.w);
}

// ---------------- concat ----------------

__global__ void concat_init_kernel(const float4* __restrict__ u,
                                   const float4* __restrict__ res,
                                   float4* __restrict__ bufA,
                                   float4* __restrict__ out,
                                   int user4, int total4)
{
    int i = blockIdx.x * blockDim.x + threadIdx.x;
    if (i >= total4) return;
    float4 v = (i < user4) ? u[i] : res[i - user4];
    bufA[i] = v;
    out[i] = v;
}

// ---------------- CSR build: histogram -> 3-phase scan -> scatter ----------------

__global__ void hist_kernel(const int* __restrict__ row, int* __restrict__ counts, int nnz)
{
    int i = blockIdx.x * blockDim.x + threadIdx.x;
    if (i < nnz) atomicAdd(&counts[row[i]], 1);
}

// phase 1: per-block (1024 elems) local exclusive scan + block total
__global__ __launch_bounds__(256) void block_scan_kernel(
    const int* __restrict__ counts, int* __restrict__ local_scan,
    int* __restrict__ block_sums, int n)
{
    __shared__ int wsum[4];
    int tid  = threadIdx.x;
    int lane = tid & 63;
    int wave = tid >> 6;
    int base = blockIdx.x * 1024 + tid * 4;

    int4 v = make_int4(0, 0, 0, 0);
    if (base + 3 < n) {
        v = *(const int4*)(counts + base);
    } else {
        if (base + 0 < n) v.x = counts[base + 0];
        if (base + 1 < n) v.y = counts[base + 1];
        if (base + 2 < n) v.z = counts[base + 2];
        if (base + 3 < n) v.w = counts[base + 3];
    }
    int total = v.x + v.y + v.z + v.w;

    int incl = total;
#pragma unroll
    for (int off = 1; off < 64; off <<= 1) {
        int u = __shfl_up(incl, off, 64);
        if (lane >= off) incl += u;
    }
    if (lane == 63) wsum[wave] = incl;
    __syncthreads();
    int woff = 0;
    for (int w = 0; w < wave; ++w) woff += wsum[w];
    int excl = woff + incl - total;

    if (tid == 255) block_sums[blockIdx.x] = woff + incl;

    int p0 = excl;
    int p1 = p0 + v.x;
    int p2 = p1 + v.y;
    int p3 = p2 + v.z;
    if (base + 3 < n) {
        *(int4*)(local_scan + base) = make_int4(p0, p1, p2, p3);
    } else {
        if (base + 0 < n) local_scan[base + 0] = p0;
        if (base + 1 < n) local_scan[base + 1] = p1;
        if (base + 2 < n) local_scan[base + 2] = p2;
        if (base + 3 < n) local_scan[base + 3] = p3;
    }
}

// phase 2: single block scans block totals (nb <= 256) -> exclusive offsets
__global__ __launch_bounds__(256) void scan_blocksums_kernel(
    const int* __restrict__ block_sums, int* __restrict__ block_offs,
    int* __restrict__ row_ptr, int n, int nb)
{
    __shared__ int lds[256];
    int tid = threadIdx.x;
    int v = (tid < nb) ? block_sums[tid] : 0;
    lds[tid] = v;
    __syncthreads();
    for (int off = 1; off < 256; off <<= 1) {
        int t = (tid >= off) ? lds[tid - off] : 0;
        __syncthreads();
        lds[tid] += t;
        __syncthreads();
    }
    block_offs[tid] = lds[tid] - v;
    if (tid == nb - 1) row_ptr[n] = lds[tid];
}

// phase 3: add block offsets, materialize row_ptr + cursor
__global__ void apply_offsets_kernel(const int* __restrict__ local_scan,
                                     const int* __restrict__ block_offs,
                                     int* __restrict__ row_ptr,
                                     int* __restrict__ cursor, int n)
{
    int i = blockIdx.x * blockDim.x + threadIdx.x;
    if (i >= n) return;
    int v = local_scan[i] + block_offs[i >> 10];
    row_ptr[i] = v;
    cursor[i]  = v;
}

// XCD-phased scatter: blocks with (blockIdx & 7) == p land on XCD p under the
// round-robin dispatch and handle only rows in [p*rpp, (p+1)*rpp). All writes
// to a given contiguous ~2MB slice of pair[] then come from ONE XCD's L2, so
// the ~8 partial 8B writes per 64B sector merge into full lines before
// writeback (kills the 8x write amplification seen as WRITE_SIZE=125MB).
// Streaming re-reads of row/col/val (x8) are nontemporal so they don't evict
// the dirty write region.
__global__ __launch_bounds__(256) void scatter_phase_kernel(
    const int* __restrict__ row, const int* __restrict__ col,
    const float* __restrict__ val,
    int* __restrict__ cursor, int2* __restrict__ pair, int nnz, int rpp)
{
    int phase = blockIdx.x & 7;
    int i = (blockIdx.x >> 3) * 256 + threadIdx.x;
    if (i >= nnz) return;
    int r = __builtin_nontemporal_load(row + i);
    int lo = phase * rpp;
    if ((unsigned)(r - lo) < (unsigned)rpp) {
        int c = __builtin_nontemporal_load(col + i);
        float v = __builtin_nontemporal_load(val + i);
        int pos = atomicAdd(&cursor[r], 1);
        pair[pos] = make_int2(c, __float_as_int(v));
    }
}

// ---------------- gather SpMM: wave per row, unroll-4 for MLP ----------------

__global__ __launch_bounds__(256) void spmm_csr_kernel(
    const int* __restrict__ row_ptr, const int2* __restrict__ pair,
    const float* __restrict__ cur, float* __restrict__ nxt,
    float* __restrict__ out, int n_rows)
{
    int row = blockIdx.x * 4 + (threadIdx.x >> 6);
    if (row >= n_rows) return;
    int lane = threadIdx.x & 63;

    int s = row_ptr[row];
    int e = row_ptr[row + 1];

    float acc0 = 0.0f, acc1 = 0.0f, acc2 = 0.0f, acc3 = 0.0f;
    int i = s;
    for (; i + 4 <= e; i += 4) {
        int2 p0 = pair[i + 0];
        int2 p1 = pair[i + 1];
        int2 p2 = pair[i + 2];
        int2 p3 = pair[i + 3];
        float x0 = cur[(size_t)p0.x * D + lane];
        float x1 = cur[(size_t)p1.x * D + lane];
        float x2 = cur[(size_t)p2.x * D + lane];
        float x3 = cur[(size_t)p3.x * D + lane];
        acc0 = fmaf(__int_as_float(p0.y), x0, acc0);
        acc1 = fmaf(__int_as_float(p1.y), x1, acc1);
        acc2 = fmaf(__int_as_float(p2.y), x2, acc2);
        acc3 = fmaf(__int_as_float(p3.y), x3, acc3);
    }
    for (; i < e; ++i) {
        int2 p = pair[i];
        acc0 = fmaf(__int_as_float(p.y), cur[(size_t)p.x * D + lane], acc0);
    }
    float acc = (acc0 + acc1) + (acc2 + acc3);

    size_t idx = (size_t)row * D + lane;
    nxt[idx] = acc;
    out[idx] += acc;
}

// ---------------- launch ----------------

extern "C" void kernel_launch(void* const* d_in, const int* in_sizes, int n_in,
                              void* d_out, int out_size, void* d_ws, size_t ws_size,
                              hipStream_t stream)
{
    const float* uE      = (const float*)d_in[0];
    const float* eE      = (const float*)d_in[1];
    const float* rE      = (const float*)d_in[2];
    const float* adj_val = (const float*)d_in[3];
    const int*   e_head  = (const int*)d_in[4];
    const int*   e_tail  = (const int*)d_in[5];
    const int*   e_type  = (const int*)d_in[6];
    const int*   a_row   = (const int*)d_in[7];
    const int*   a_col   = (const int*)d_in[8];

    const int n_user  = in_sizes[0] / D;   // 100000
    const int n_ent   = in_sizes[1] / D;   // 200000
    const int nnz     = in_sizes[3];       // 2000000
    const int n_edges = in_sizes[4];       // 500000
    const int n_rows  = out_size / D;      // 150000

    float* ws = (float*)d_ws;
    const size_t entElems = (size_t)n_ent * D;           // 12.8M floats
    float* sums    = ws;                                  // later: GCN bufA
    float* cnt     = ws + entElems;
    float* ent1    = ws + entElems + n_ent;               // later: GCN bufB
    float* ent_res = ws + 2 * entElems + n_ent;           // later: CSR arrays

    int*  row_ptr    = (int*)ent_res;                     // n_rows+1
    int*  cursor     = row_ptr + (n_rows + 1);            // n_rows+1 (aliases counts)
    int2* pair       = (int2*)(cursor + n_rows + 1);      // nnz (8B each)
    int*  local_scan = (int*)(pair + nnz);                // n_rows (int4-aligned)
    int*  block_sums = local_scan + n_rows + 4;           // <=256
    int*  block_offs = block_sums + 256;                  // 256

    float* out = (float*)d_out;

    const int edge_blocks = (n_edges + 15) / 16;
    const int ent_blocks  = (n_ent + 15) / 16;

    // ---- RGAT hop 1 ----
    hipMemsetAsync(sums, 0, (entElems + n_ent) * sizeof(float), stream);
    rgat_edge_kernel<<<edge_blocks, 256, 0, stream>>>(eE, rE, e_head, e_tail, e_type,
                                                      sums, cnt, n_edges);
    finalize_hop_kernel<<<ent_blocks, 256, 0, stream>>>(sums, cnt, eE, ent1, ent_res, n_ent);

    // ---- RGAT hop 2 ----
    hipMemsetAsync(sums, 0, (entElems + n_ent) * sizeof(float), stream);
    rgat_edge_kernel<<<edge_blocks, 256, 0, stream>>>(ent1, rE, e_head, e_tail, e_type,
                                                      sums, cnt, n_edges);
    finalize_hop_kernel<<<ent_blocks, 256, 0, stream>>>(sums, cnt, ent_res, ent1, ent_res, n_ent);

    // ---- GCN ----
    float* bufA = sums;
    float* bufB = ent1;

    const int total4 = n_rows * (D / 4);
    const int user4  = n_user * (D / 4);

    concat_init_kernel<<<(total4 + 255) / 256, 256, 0, stream>>>(
        (const float4*)uE, (const float4*)ent_res, (float4*)bufA, (float4*)out,
        user4, total4);

    // build CSR of adj (reused by both layers)
    const int nb = (n_rows + 1023) / 1024;   // 147 (<=256)
    hipMemsetAsync(cursor, 0, (size_t)(n_rows + 1) * sizeof(int), stream);
    hist_kernel<<<(nnz + 255) / 256, 256, 0, stream>>>(a_row, cursor, nnz);
    block_scan_kernel<<<nb, 256, 0, stream>>>(cursor, local_scan, block_sums, n_rows);
    scan_blocksums_kernel<<<1, 256, 0, stream>>>(block_sums, block_offs, row_ptr, n_rows, nb);
    apply_offsets_kernel<<<(n_rows + 255) / 256, 256, 0, stream>>>(local_scan, block_offs,
                                                                   row_ptr, cursor, n_rows);

    const int rpp = (n_rows + 7) / 8;                     // 18750 rows per XCD phase
    const int chunk_blocks = (nnz + 255) / 256;
    scatter_phase_kernel<<<chunk_blocks * 8, 256, 0, stream>>>(a_row, a_col, adj_val,
                                                               cursor, pair, nnz, rpp);

    const int row_blocks = (n_rows + 3) / 4;
    // layer 1: bufB = A*bufA; out += bufB
    spmm_csr_kernel<<<row_blocks, 256, 0, stream>>>(row_ptr, pair, bufA, bufB, out, n_rows);
    // layer 2: bufA = A*bufB; out += bufA
    spmm_csr_kernel<<<row_blocks, 256, 0, stream>>>(row_ptr, pair, bufB, bufA, out, n_rows);
}

// Round 2
// 733.913 us; speedup vs baseline: 1.1934x; 1.1590x over previous
//
#include <hip/hip_runtime.h>
#include <math.h>

#define D 64
#define MIN_NORM 1e-15f
#define NBINS 64

#define RCP(x)  __builtin_amdgcn_rcpf(x)
#define RSQ(x)  __builtin_amdgcn_rsqf(x)

// ---------------- DPP butterfly within 16-lane rows ----------------
template <int CTRL>
__device__ __forceinline__ float dpp_sum_step(float v) {
    int iv = __builtin_bit_cast(int, v);
    int sh = __builtin_amdgcn_update_dpp(0, iv, CTRL, 0xf, 0xf, true);
    return v + __builtin_bit_cast(float, sh);
}
#define DPP_XOR1  0xB1   // quad_perm [1,0,3,2]
#define DPP_XOR2  0x4E   // quad_perm [2,3,0,1]
#define DPP_HMIR  0x141  // row_half_mirror
#define DPP_MIR   0x140  // row_mirror

__device__ __forceinline__ float row16_sum(float v) {
    v = dpp_sum_step<DPP_XOR1>(v);
    v = dpp_sum_step<DPP_XOR2>(v);
    v = dpp_sum_step<DPP_HMIR>(v);
    v = dpp_sum_step<DPP_MIR>(v);
    return v;
}

// ---------------- fast transcendentals (args >= 0) ----------------

__device__ __forceinline__ float fast_tanh_pos(float x) {
    float t = __expf(-2.0f * x);
    return (1.0f - t) * RCP(1.0f + t);
}

__device__ __forceinline__ float fast_atanh(float x) {
    return 0.5f * __logf((1.0f + x) * RCP(1.0f - x));
}

// ---------------- RGAT head kernel: 16 lanes/head, CSR edge loop ----------
// One 16-lane group per head. Head-only math hoisted out of the edge loop;
// accumulation in registers (zero atomics); mean->l2norm->residual fused.
// headperm orders heads by descending degree so the 4 groups of a wave have
// (near-)equal degree -> no divergence inflation, long heads dispatch first.

__global__ __launch_bounds__(256) void rgat_head_kernel(
    const float* __restrict__ ent, const float* __restrict__ rel,
    const int* __restrict__ erow_ptr, const int2* __restrict__ pair_e,
    const int* __restrict__ headperm,
    const float* __restrict__ prev_res,
    float* __restrict__ ent_out, float* __restrict__ res_out,
    int n_ent, int write_ent)
{
    int g = blockIdx.x * 16 + (threadIdx.x >> 4);
    if (g >= n_ent) return;
    int sub = threadIdx.x & 15;
    int h = headperm[g];

    const float* hp = ent + (size_t)h * D + sub;
    float hex = hp[0], hey = hp[16], hez = hp[32], hew = hp[48];
    float HE2 = row16_sum(hex*hex + hey*hey + hez*hez + hew*hew);

    // ---- head-only chain (hoisted) ----
    float HE2g = fmaxf(HE2, 1e-30f);
    float rNhe = RSQ(HE2g);
    float Nhe  = HE2g * rNhe;
    float a = fast_tanh_pos(Nhe) * rNhe;
    float HH2 = a * a * HE2;
    float mterm = fmaxf(1.0f - HH2, MIN_NORM);   // = 2/lam
    float rmterm = RCP(mterm);

    float ax = 0.0f, ay = 0.0f, az = 0.0f, aw = 0.0f;
    int s = erow_ptr[h];
    int e = erow_ptr[h + 1];

    for (int i = s; i < e; ++i) {
        int2 pe = pair_e[i];
        const float* tp = ent + (size_t)pe.x * D + sub;
        const float* rp = rel + (size_t)(pe.y - 1) * D + sub;
        float tex = tp[0], tey = tp[16], tez = tp[32], tew = tp[48];
        float rex = rp[0], rey = rp[16], rez = rp[32], rew = rp[48];

        float TE2 = row16_sum(tex*tex + tey*tey + tez*tez + tew*tew);
        float RE2 = row16_sum(rex*rex + rey*rey + rez*rez + rew*rew);
        float HT  = row16_sum(hex*tex + hey*tey + hez*tez + hew*tew);
        float HR  = row16_sum(hex*rex + hey*rey + hez*rez + hew*rew);
        float TR  = row16_sum(tex*rex + tey*rey + tez*rez + tew*rew);

        float S2 = TE2 + 2.0f * TR + RE2;
        float ricci_k = 1e-7f * RSQ(fmaxf(S2, 1e-24f));

        float TE2g = fmaxf(TE2, 1e-30f);
        float rNte = RSQ(TE2g);
        float b = fast_tanh_pos(TE2g * rNte * rmterm) * rNte;
        float RE2g = fmaxf(RE2, 1e-30f);
        float rNre = RSQ(RE2g);
        float c = fast_tanh_pos(RE2g * rNre * rmterm) * rNre;

        float y2t = b * b * TE2, xyt = a * b * HT;
        float A1 = 1.0f + 2.0f * xyt + y2t, B1 = 1.0f - HH2;
        float r_d1 = RCP(fmaxf(1.0f + 2.0f * xyt + HH2 * y2t, MIN_NORM));
        float p1 = A1 * a * r_d1, q1 = B1 * b * r_d1;
        float HT2 = fmaxf((A1*A1*HH2 + 2.0f*A1*B1*xyt + B1*B1*y2t) * r_d1 * r_d1, 0.0f);

        float y2r = c * c * RE2, xyr = a * c * HR;
        float A2 = 1.0f + 2.0f * xyr + y2r, B2 = 1.0f - HH2;
        float r_d2 = RCP(fmaxf(1.0f + 2.0f * xyr + HH2 * y2r, MIN_NORM));
        float p2 = A2 * a * r_d2, q2 = B2 * c * r_d2;
        float HR2 = fmaxf((A2*A2*HH2 + 2.0f*A2*B2*xyr + B2*B2*y2r) * r_d2 * r_d2, 0.0f);

        float xy3 = p1*p2*HE2 + p1*q2*HR + q1*p2*HT + q1*q2*TR;
        float A3 = 1.0f + 2.0f * xy3 + HR2, B3 = 1.0f - HT2;
        float r_d3 = RCP(fmaxf(1.0f + 2.0f * xy3 + HT2 * HR2, MIN_NORM));
        float al = (A3 * p1 + B3 * p2) * r_d3;
        float be = A3 * q1 * r_d3;
        float ga = B3 * q2 * r_d3;
        float R2 = fmaxf((A3*A3*HT2 + 2.0f*A3*B3*xy3 + B3*B3*HR2) * r_d3 * r_d3, 0.0f);

        float R2g = fmaxf(R2, 1e-30f);
        float rNr = RSQ(R2g);
        float Nr  = R2g * rNr;
        const float maxn = 1.0f - 1e-3f;
        if (Nr > maxn) {
            float sc = maxn * rNr;
            al *= sc; be *= sc; ga *= sc;
            R2 = maxn * maxn;
        }

        float dhr = a * (al * HE2 + be * HT + ga * HR);
        float xy4 = -dhr;
        float A4 = 1.0f + 2.0f * xy4 + R2, B4 = 1.0f - HH2;
        float r_d4 = RCP(fmaxf(1.0f + 2.0f * xy4 + HH2 * R2, MIN_NORM));
        float sh = (-A4 * a + B4 * al) * r_d4;
        float st = B4 * be * r_d4;
        float sr = B4 * ga * r_d4;
        float SUB2 = fmaxf((A4*A4*HH2 + 2.0f*A4*B4*xy4 + B4*B4*R2) * r_d4 * r_d4, 0.0f);

        float SUB2g = fmaxf(SUB2, 1e-30f);
        float rNsub = RSQ(SUB2g);
        float Nsub  = SUB2g * rNsub;
        float k = mterm * fast_atanh(fminf(Nsub, 1.0f - 1e-5f)) * rNsub;

        float kh = k * sh;
        float kt = k * st + ricci_k;
        float kr = k * sr + ricci_k;

        ax += fmaxf(kh*hex + kt*tex + kr*rex, 0.0f);
        ay += fmaxf(kh*hey + kt*tey + kr*rey, 0.0f);
        az += fmaxf(kh*hez + kt*tez + kr*rez, 0.0f);
        aw += fmaxf(kh*hew + kt*tew + kr*rew, 0.0f);
    }

    // ---- fused finalize: mean -> l2norm -> residual ----
    float rc = RCP(fmaxf((float)(e - s), 1.0f));
    float mx = ax*rc, my = ay*rc, mz = az*rc, mw = aw*rc;
    float M2 = row16_sum(mx*mx + my*my + mz*mz + mw*mw);
    float rn = RSQ(fmaxf(M2, 1e-24f));
    mx *= rn; my *= rn; mz *= rn; mw *= rn;

    if (write_ent) {
        float* ep = ent_out + (size_t)h * D + sub;
        ep[0] = mx; ep[16] = my; ep[32] = mz; ep[48] = mw;
    }
    const float* pp = prev_res + (size_t)h * D + sub;
    float* rp2 = res_out + (size_t)h * D + sub;
    rp2[0]  = 0.5f*pp[0]  + mx;
    rp2[16] = 0.5f*pp[16] + my;
    rp2[32] = 0.5f*pp[32] + mz;
    rp2[48] = 0.5f*pp[48] + mw;
}

// ---------------- degree counting sort (64 bins, descending) ----------------

__global__ __launch_bounds__(256) void deg_hist_kernel(
    const int* __restrict__ erow_ptr, int* __restrict__ dbins, int n_heads)
{
    __shared__ int lbin[NBINS];
    int tid = threadIdx.x;
    if (tid < NBINS) lbin[tid] = 0;
    __syncthreads();
    int h = blockIdx.x * 256 + tid;
    if (h < n_heads) {
        int d = min(erow_ptr[h + 1] - erow_ptr[h], NBINS - 1);
        atomicAdd(&lbin[d], 1);
    }
    __syncthreads();
    if (tid < NBINS) { int c = lbin[tid]; if (c) atomicAdd(&dbins[tid], c); }
}

// single wave: descending-order bin bases (largest degree at position 0)
__global__ void deg_scan_kernel(const int* __restrict__ dbins, int* __restrict__ bin_cursor)
{
    int tid = threadIdx.x;   // 64 threads
    int v = dbins[tid];
    int incl = v;
#pragma unroll
    for (int off = 1; off < 64; off <<= 1) {
        int u = __shfl_up(incl, off, 64);
        if (tid >= off) incl += u;
    }
    int T = __shfl(incl, 63, 64);
    bin_cursor[tid] = T - incl;   // descending layout: bin 63 first
}

__global__ __launch_bounds__(256) void deg_scatter_kernel(
    const int* __restrict__ erow_ptr, int* __restrict__ bin_cursor,
    int* __restrict__ headperm, int n_heads)
{
    __shared__ int lbin[NBINS];
    __shared__ int lbase[NBINS];
    int tid = threadIdx.x;
    if (tid < NBINS) lbin[tid] = 0;
    __syncthreads();
    int h = blockIdx.x * 256 + tid;
    int b = 0, lpos = 0;
    bool act = (h < n_heads);
    if (act) {
        b = min(erow_ptr[h + 1] - erow_ptr[h], NBINS - 1);
        lpos = atomicAdd(&lbin[b], 1);
    }
    __syncthreads();
    if (tid < NBINS) { int c = lbin[tid]; lbase[tid] = c ? atomicAdd(&bin_cursor[tid], c) : 0; }
    __syncthreads();
    if (act) headperm[lbase[b] + lpos] = h;
}

// ---------------- concat ----------------

__global__ void concat_init_kernel(const float4* __restrict__ u,
                                   const float4* __restrict__ res,
                                   float4* __restrict__ bufA,
                                   float4* __restrict__ out,
                                   int user4, int total4)
{
    int i = blockIdx.x * blockDim.x + threadIdx.x;
    if (i >= total4) return;
    float4 v = (i < user4) ? u[i] : res[i - user4];
    bufA[i] = v;
    out[i] = v;
}

// ---------------- CSR build: histogram -> 3-phase scan -> scatter ----------------

__global__ void hist_kernel(const int* __restrict__ row, int* __restrict__ counts, int nnz)
{
    int i = blockIdx.x * blockDim.x + threadIdx.x;
    if (i < nnz) atomicAdd(&counts[row[i]], 1);
}

// phase 1: per-block (1024 elems) local exclusive scan + block total
__global__ __launch_bounds__(256) void block_scan_kernel(
    const int* __restrict__ counts, int* __restrict__ local_scan,
    int* __restrict__ block_sums, int n)
{
    __shared__ int wsum[4];
    int tid  = threadIdx.x;
    int lane = tid & 63;
    int wave = tid >> 6;
    int base = blockIdx.x * 1024 + tid * 4;

    int4 v = make_int4(0, 0, 0, 0);
    if (base + 3 < n) {
        v = *(const int4*)(counts + base);
    } else {
        if (base + 0 < n) v.x = counts[base + 0];
        if (base + 1 < n) v.y = counts[base + 1];
        if (base + 2 < n) v.z = counts[base + 2];
        if (base + 3 < n) v.w = counts[base + 3];
    }
    int total = v.x + v.y + v.z + v.w;

    int incl = total;
#pragma unroll
    for (int off = 1; off < 64; off <<= 1) {
        int u = __shfl_up(incl, off, 64);
        if (lane >= off) incl += u;
    }
    if (lane == 63) wsum[wave] = incl;
    __syncthreads();
    int woff = 0;
    for (int w = 0; w < wave; ++w) woff += wsum[w];
    int excl = woff + incl - total;

    if (tid == 255) block_sums[blockIdx.x] = woff + incl;

    int p0 = excl;
    int p1 = p0 + v.x;
    int p2 = p1 + v.y;
    int p3 = p2 + v.z;
    if (base + 3 < n) {
        *(int4*)(local_scan + base) = make_int4(p0, p1, p2, p3);
    } else {
        if (base + 0 < n) local_scan[base + 0] = p0;
        if (base + 1 < n) local_scan[base + 1] = p1;
        if (base + 2 < n) local_scan[base + 2] = p2;
        if (base + 3 < n) local_scan[base + 3] = p3;
    }
}

// phase 2: single block scans block totals (nb <= 256) -> exclusive offsets
__global__ __launch_bounds__(256) void scan_blocksums_kernel(
    const int* __restrict__ block_sums, int* __restrict__ block_offs,
    int* __restrict__ row_ptr, int n, int nb)
{
    __shared__ int lds[256];
    int tid = threadIdx.x;
    int v = (tid < nb) ? block_sums[tid] : 0;
    lds[tid] = v;
    __syncthreads();
    for (int off = 1; off < 256; off <<= 1) {
        int t = (tid >= off) ? lds[tid - off] : 0;
        __syncthreads();
        lds[tid] += t;
        __syncthreads();
    }
    block_offs[tid] = lds[tid] - v;
    if (tid == nb - 1) row_ptr[n] = lds[tid];
}

// phase 3: add block offsets, materialize row_ptr + cursor
__global__ void apply_offsets_kernel(const int* __restrict__ local_scan,
                                     const int* __restrict__ block_offs,
                                     int* __restrict__ row_ptr,
                                     int* __restrict__ cursor, int n)
{
    int i = blockIdx.x * blockDim.x + threadIdx.x;
    if (i >= n) return;
    int v = local_scan[i] + block_offs[i >> 10];
    row_ptr[i] = v;
    cursor[i]  = v;
}

// XCD-phased scatter: blocks with (blockIdx & 7) == p land on XCD p under the
// round-robin dispatch and handle only rows in [p*rpp, (p+1)*rpp). All writes
// to a given contiguous slice of pair[] then come from ONE XCD's L2, so the
// partial 8B writes per 64B sector merge into full lines before writeback.
__global__ __launch_bounds__(256) void scatter_phase_kernel(
    const int* __restrict__ row, const int* __restrict__ col,
    const float* __restrict__ val,
    int* __restrict__ cursor, int2* __restrict__ pair, int nnz, int rpp)
{
    int phase = blockIdx.x & 7;
    int i = (blockIdx.x >> 3) * 256 + threadIdx.x;
    if (i >= nnz) return;
    int r = __builtin_nontemporal_load(row + i);
    int lo = phase * rpp;
    if ((unsigned)(r - lo) < (unsigned)rpp) {
        int c = __builtin_nontemporal_load(col + i);
        float v = __builtin_nontemporal_load(val + i);
        int pos = atomicAdd(&cursor[r], 1);
        pair[pos] = make_int2(c, __float_as_int(v));
    }
}

// ---------------- gather SpMM: wave per row, unroll-4 for MLP ----------------

__global__ __launch_bounds__(256) void spmm_csr_kernel(
    const int* __restrict__ row_ptr, const int2* __restrict__ pair,
    const float* __restrict__ cur, float* __restrict__ nxt,
    float* __restrict__ out, int n_rows)
{
    int row = blockIdx.x * 4 + (threadIdx.x >> 6);
    if (row >= n_rows) return;
    int lane = threadIdx.x & 63;

    int s = row_ptr[row];
    int e = row_ptr[row + 1];

    float acc0 = 0.0f, acc1 = 0.0f, acc2 = 0.0f, acc3 = 0.0f;
    int i = s;
    for (; i + 4 <= e; i += 4) {
        int2 p0 = pair[i + 0];
        int2 p1 = pair[i + 1];
        int2 p2 = pair[i + 2];
        int2 p3 = pair[i + 3];
        float x0 = cur[(size_t)p0.x * D + lane];
        float x1 = cur[(size_t)p1.x * D + lane];
        float x2 = cur[(size_t)p2.x * D + lane];
        float x3 = cur[(size_t)p3.x * D + lane];
        acc0 = fmaf(__int_as_float(p0.y), x0, acc0);
        acc1 = fmaf(__int_as_float(p1.y), x1, acc1);
        acc2 = fmaf(__int_as_float(p2.y), x2, acc2);
        acc3 = fmaf(__int_as_float(p3.y), x3, acc3);
    }
    for (; i < e; ++i) {
        int2 p = pair[i];
        acc0 = fmaf(__int_as_float(p.y), cur[(size_t)p.x * D + lane], acc0);
    }
    float acc = (acc0 + acc1) + (acc2 + acc3);

    size_t idx = (size_t)row * D + lane;
    nxt[idx] = acc;
    out[idx] += acc;
}

// ---------------- launch ----------------

extern "C" void kernel_launch(void* const* d_in, const int* in_sizes, int n_in,
                              void* d_out, int out_size, void* d_ws, size_t ws_size,
                              hipStream_t stream)
{
    const float* uE      = (const float*)d_in[0];
    const float* eE      = (const float*)d_in[1];
    const float* rE      = (const float*)d_in[2];
    const float* adj_val = (const float*)d_in[3];
    const int*   e_head  = (const int*)d_in[4];
    const int*   e_tail  = (const int*)d_in[5];
    const int*   e_type  = (const int*)d_in[6];
    const int*   a_row   = (const int*)d_in[7];
    const int*   a_col   = (const int*)d_in[8];

    const int n_user  = in_sizes[0] / D;   // 100000
    const int n_ent   = in_sizes[1] / D;   // 200000
    const int nnz     = in_sizes[3];       // 2000000
    const int n_edges = in_sizes[4];       // 500000
    const int n_rows  = out_size / D;      // 150000

    float* ws = (float*)d_ws;
    const size_t entElems = (size_t)n_ent * D;           // 12.8M floats
    float* ent1    = ws;                                  // [n_ent][D]; later GCN bufA
    float* ent_res = ws + entElems;                       // [n_ent][D]; later GCN bufB
    int*   r3      = (int*)(ws + 2 * entElems);           // scratch: edge-CSR then adj-CSR

    // ---- edge-CSR (by head) + degree-sort layout (alive during hops) ----
    const int nep = n_ent + 4;                            // padded, keeps 16B alignment
    int*  erow_ptr = r3;                                  // n_ent+1
    int*  ecursor  = erow_ptr + nep;                      // n_ent+1 (counts/cursor)
    int2* pair_e   = (int2*)(ecursor + nep);              // n_edges (tail, type-bits)
    int*  headperm = (int*)(pair_e + n_edges);            // n_ent
    int*  elocal   = headperm + n_ent;                    // n_ent
    int*  ebsums   = elocal + n_ent;                      // 256
    int*  eboffs   = ebsums + 256;                        // 256
    int*  dbins    = eboffs + 256;                        // 64
    int*  bincur   = dbins + NBINS;                       // 64

    // ---- adj-CSR layout (alive during GCN; overlaps edge-CSR, sequential) ----
    int*  row_ptr    = r3;                                // n_rows+1
    int*  cursor     = row_ptr + (n_rows + 4);            // n_rows+1
    int2* pair       = (int2*)(cursor + n_rows + 4);      // nnz
    int*  local_scan = (int*)(pair + nnz);                // n_rows
    int*  block_sums = local_scan + n_rows;               // 256
    int*  block_offs = block_sums + 256;                  // 256

    float* out = (float*)d_out;

    // ================= edge-CSR build + degree sort (once) =================
    const int enb = (n_ent + 1023) / 1024;                // 196 <= 256
    hipMemsetAsync(ecursor, 0, (size_t)nep * sizeof(int), stream);
    hipMemsetAsync(dbins, 0, 2 * NBINS * sizeof(int), stream);
    hist_kernel<<<(n_edges + 255) / 256, 256, 0, stream>>>(e_head, ecursor, n_edges);
    block_scan_kernel<<<enb, 256, 0, stream>>>(ecursor, elocal, ebsums, n_ent);
    scan_blocksums_kernel<<<1, 256, 0, stream>>>(ebsums, eboffs, erow_ptr, n_ent, enb);
    apply_offsets_kernel<<<(n_ent + 255) / 256, 256, 0, stream>>>(elocal, eboffs,
                                                                  erow_ptr, ecursor, n_ent);
    const int erpp = (n_ent + 7) / 8;
    scatter_phase_kernel<<<((n_edges + 255) / 256) * 8, 256, 0, stream>>>(
        e_head, e_tail, (const float*)e_type, ecursor, pair_e, n_edges, erpp);
    deg_hist_kernel<<<(n_ent + 255) / 256, 256, 0, stream>>>(erow_ptr, dbins, n_ent);
    deg_scan_kernel<<<1, 64, 0, stream>>>(dbins, bincur);
    deg_scatter_kernel<<<(n_ent + 255) / 256, 256, 0, stream>>>(erow_ptr, bincur,
                                                                headperm, n_ent);

    // ================= RGAT hops (no atomics, no memset, fused finalize) ====
    const int head_blocks = (n_ent + 15) / 16;
    rgat_head_kernel<<<head_blocks, 256, 0, stream>>>(eE, rE, erow_ptr, pair_e, headperm,
                                                      eE, ent1, ent_res, n_ent, 1);
    rgat_head_kernel<<<head_blocks, 256, 0, stream>>>(ent1, rE, erow_ptr, pair_e, headperm,
                                                      ent_res, ent1, ent_res, n_ent, 0);

    // ================= GCN =================
    float* bufA = ent1;      // 150K x 64 <= ent1 region
    float* bufB = ent_res;   // consumed by concat before spmm overwrites it

    const int total4 = n_rows * (D / 4);
    const int user4  = n_user * (D / 4);

    concat_init_kernel<<<(total4 + 255) / 256, 256, 0, stream>>>(
        (const float4*)uE, (const float4*)ent_res, (float4*)bufA, (float4*)out,
        user4, total4);

    // build CSR of adj (reused by both layers) — overwrites dead edge-CSR
    const int nb = (n_rows + 1023) / 1024;   // 147 (<=256)
    hipMemsetAsync(cursor, 0, (size_t)(n_rows + 1) * sizeof(int), stream);
    hist_kernel<<<(nnz + 255) / 256, 256, 0, stream>>>(a_row, cursor, nnz);
    block_scan_kernel<<<nb, 256, 0, stream>>>(cursor, local_scan, block_sums, n_rows);
    scan_blocksums_kernel<<<1, 256, 0, stream>>>(block_sums, block_offs, row_ptr, n_rows, nb);
    apply_offsets_kernel<<<(n_rows + 255) / 256, 256, 0, stream>>>(local_scan, block_offs,
                                                                   row_ptr, cursor, n_rows);
    const int rpp = (n_rows + 7) / 8;
    scatter_phase_kernel<<<((nnz + 255) / 256) * 8, 256, 0, stream>>>(
        a_row, a_col, adj_val, cursor, pair, nnz, rpp);

    const int row_blocks = (n_rows + 3) / 4;
    // layer 1: bufB = A*bufA; out += bufB
    spmm_csr_kernel<<<row_blocks, 256, 0, stream>>>(row_ptr, pair, bufA, bufB, out, n_rows);
    // layer 2: bufA = A*bufB; out += bufA
    spmm_csr_kernel<<<row_blocks, 256, 0, stream>>>(row_ptr, pair, bufB, bufA, out, n_rows);
}